// Round 1
// baseline (110.696 us; speedup 1.0000x reference)
//
#include <hip/hip_runtime.h>

typedef __attribute__((ext_vector_type(8))) _Float16 f16x8;
typedef __attribute__((ext_vector_type(4))) float f32x4;
typedef __attribute__((address_space(1))) const char gc_char;
typedef __attribute__((address_space(3))) char ls_char;

#define MFMA(a, b, c) __builtin_amdgcn_mfma_f32_16x16x32_f16((a), (b), (c), 0, 0, 0)

static constexpr int SEQ = 4096;
static constexpr int EMB = 512;
static constexpr int NBATCH = 4;
static constexpr float QSCALE = 0.04419417382415922f; // 1/sqrt(512)

__device__ __forceinline__ void gl_lds16(const void* g, void* l) {
    __builtin_amdgcn_global_load_lds((gc_char*)g, (ls_char*)l, 16, 0, 0);
}

// ---------------- cast x (fp32 -> fp16), 8 elems/thread ----------------
__global__ void k_cast_x(const float* __restrict__ x, _Float16* __restrict__ xb) {
    long i = (long)blockIdx.x * 256 + threadIdx.x; // over n/8
    const float4* p = (const float4*)x + i * 2;
    float4 a = p[0], b = p[1];
    f16x8 v;
    v[0] = (_Float16)a.x; v[1] = (_Float16)a.y; v[2] = (_Float16)a.z; v[3] = (_Float16)a.w;
    v[4] = (_Float16)b.x; v[5] = (_Float16)b.y; v[6] = (_Float16)b.z; v[7] = (_Float16)b.w;
    *(f16x8*)(xb + i * 8) = v;
}

// ---------------- transpose-cast W [512][N] -> WT [N][512] fp16 ----------------
__global__ void k_transpose_cast(const float* __restrict__ W, _Float16* __restrict__ WT, int Ncols) {
    int i = blockIdx.x * 256 + threadIdx.x; // over Ncols*512
    if (i >= Ncols * 512) return;
    int n = i >> 9, k = i & 511;
    WT[i] = (_Float16)W[k * Ncols + n];
}

// ---------------- GEMM: C[M,N] = A[M,512] * BT[N,512]^T + bias ----------------
// EPI 0: split to Q(scaled)/K/V fp16.  EPI 1: fp32 out.
template <int EPI>
__launch_bounds__(256, 2) __global__
void k_gemm(const _Float16* __restrict__ A, const _Float16* __restrict__ BT,
            const float* __restrict__ bias, void* o0, void* o1, void* o2) {
    __shared__ __align__(16) _Float16 As[128 * 64];
    __shared__ __align__(16) _Float16 Bs[128 * 64];
    const int tid = threadIdx.x, w = tid >> 6, lane = tid & 63, g = lane >> 4, f = lane & 15;
    const int wr = w >> 1, wc = w & 1;
    const long row0 = (long)blockIdx.x * 128, col0 = (long)blockIdx.y * 128;
    f32x4 acc[4][4] = {};
    const char* Ab = (const char*)(A + row0 * 512);
    const char* Bb = (const char*)(BT + col0 * 512);

    for (int kt = 0; kt < 8; ++kt) {
        __syncthreads();
        const char* Asrc = Ab + kt * 128; // 64 fp16 = 128 B along K
        const char* Bsrc = Bb + kt * 128;
#pragma unroll
        for (int it = 0; it < 4; ++it) {
            int slot = it * 256 + tid;
            int r = slot >> 3, ch = slot & 7;
            int scol = (ch * 16) ^ ((r & 7) << 4); // pre-swizzled source
            gl_lds16(Asrc + (long)r * 1024 + scol, (char*)As + (it * 256 + (tid & 0xC0)) * 16);
            gl_lds16(Bsrc + (long)r * 1024 + scol, (char*)Bs + (it * 256 + (tid & 0xC0)) * 16);
        }
        __syncthreads();
#pragma unroll
        for (int ks = 0; ks < 2; ++ks) {
            f16x8 af[4], bf[4];
#pragma unroll
            for (int mi = 0; mi < 4; ++mi) {
                int r = wr * 64 + mi * 16 + f;
                af[mi] = *(const f16x8*)((const char*)As + r * 128 + ((ks * 64 + g * 16) ^ ((r & 7) << 4)));
            }
#pragma unroll
            for (int ni = 0; ni < 4; ++ni) {
                int r = wc * 64 + ni * 16 + f;
                bf[ni] = *(const f16x8*)((const char*)Bs + r * 128 + ((ks * 64 + g * 16) ^ ((r & 7) << 4)));
            }
#pragma unroll
            for (int mi = 0; mi < 4; ++mi)
#pragma unroll
                for (int ni = 0; ni < 4; ++ni)
                    acc[mi][ni] = MFMA(af[mi], bf[ni], acc[mi][ni]);
        }
    }

    // epilogue: D row = (lane>>4)*4+j within 16-tile, D col = lane&15
#pragma unroll
    for (int mi = 0; mi < 4; ++mi) {
#pragma unroll
        for (int ni = 0; ni < 4; ++ni) {
            long r0 = row0 + wr * 64 + mi * 16 + g * 4;
            int c = (int)col0 + wc * 64 + ni * 16 + f;
            float bv = bias[c];
#pragma unroll
            for (int j = 0; j < 4; ++j) {
                float v = acc[mi][ni][j] + bv;
                long r = r0 + j;
                if (EPI == 0) {
                    if (c < 512)
                        ((_Float16*)o0)[r * 512 + c] = (_Float16)(v * QSCALE);
                    else if (c < 1024)
                        ((_Float16*)o1)[r * 512 + (c - 512)] = (_Float16)v;
                    else
                        ((_Float16*)o2)[r * 512 + (c - 1024)] = (_Float16)v;
                } else {
                    ((float*)o0)[r * 512 + c] = v;
                }
            }
        }
    }
}

// ---------------- windowed attention ----------------
// block = (batch, 64-query tile), 256 threads = 4 waves; key span 192 (q0-64 .. q0+127)
__launch_bounds__(256, 2) __global__
void k_attn(const _Float16* __restrict__ Qb, const _Float16* __restrict__ Kb,
            const _Float16* __restrict__ Vb, _Float16* __restrict__ Ob) {
    __shared__ __align__(16) _Float16 Pl[64 * 200]; // [row q][key col], pad->stride 400B
    __shared__ __align__(16) _Float16 VT[64 * 200]; // [e][key], pad->stride 400B
    const int tid = threadIdx.x, w = tid >> 6, lane = tid & 63, g = lane >> 4, f = lane & 15;
    const int b = blockIdx.x >> 6, qt = blockIdx.x & 63;
    const int q0 = qt * 64, kbase = q0 - 64;

    // Q fragments for this wave's 16 rows, whole K=512 (A operand)
    const _Float16* qrow = Qb + ((long)(b * SEQ + q0 + w * 16 + f)) * EMB + g * 8;
    f16x8 qf[16];
#pragma unroll
    for (int ks = 0; ks < 16; ++ks) qf[ks] = *(const f16x8*)(qrow + ks * 32);

    // K fragment base pointers (B operand: lane&15 = key index within 16-tile)
    const _Float16* kp[12];
#pragma unroll
    for (int t = 0; t < 12; ++t) {
        int key = kbase + t * 16 + f;
        key = min(max(key, 0), SEQ - 1);
        kp[t] = Kb + ((long)(b * SEQ + key)) * EMB + g * 8;
    }

    f32x4 sacc[12] = {};
#pragma unroll
    for (int ks = 0; ks < 16; ++ks) {
#pragma unroll
        for (int t = 0; t < 12; ++t)
            sacc[t] = MFMA(qf[ks], *(const f16x8*)(kp[t] + ks * 32), sacc[t]);
    }

    // mask + wave-parallel softmax (row lives in 16 lanes: shfl_xor 1,2,4,8)
    const int qr0 = q0 + w * 16 + g * 4;
    float m[4] = {-3e30f, -3e30f, -3e30f, -3e30f}, l[4] = {0.f, 0.f, 0.f, 0.f};
#pragma unroll
    for (int t = 0; t < 12; ++t) {
        int key = kbase + t * 16 + f;
        bool kv = (key >= 0) && (key < SEQ);
#pragma unroll
        for (int j = 0; j < 4; ++j) {
            int d = key - (qr0 + j);
            bool valid = kv && (d >= -64) && (d <= 64);
            float s = valid ? sacc[t][j] : -3e30f;
            sacc[t][j] = s;
            m[j] = fmaxf(m[j], s);
        }
    }
#pragma unroll
    for (int j = 0; j < 4; ++j) {
        m[j] = fmaxf(m[j], __shfl_xor(m[j], 1));
        m[j] = fmaxf(m[j], __shfl_xor(m[j], 2));
        m[j] = fmaxf(m[j], __shfl_xor(m[j], 4));
        m[j] = fmaxf(m[j], __shfl_xor(m[j], 8));
    }
#pragma unroll
    for (int t = 0; t < 12; ++t) {
#pragma unroll
        for (int j = 0; j < 4; ++j) {
            float p = __expf(sacc[t][j] - m[j]);
            sacc[t][j] = p;
            l[j] += p;
        }
    }
#pragma unroll
    for (int j = 0; j < 4; ++j) {
        l[j] += __shfl_xor(l[j], 1);
        l[j] += __shfl_xor(l[j], 2);
        l[j] += __shfl_xor(l[j], 4);
        l[j] += __shfl_xor(l[j], 8);
    }
    float rl[4];
#pragma unroll
    for (int j = 0; j < 4; ++j) rl[j] = 1.f / l[j];

    // P -> LDS (C layout scatter; 2B writes, conflict-free pattern)
#pragma unroll
    for (int t = 0; t < 12; ++t)
#pragma unroll
        for (int j = 0; j < 4; ++j)
            Pl[(w * 16 + g * 4 + j) * 200 + t * 16 + f] = (_Float16)sacc[t][j];
    __syncthreads();

    // P fragments (A operand for PV): 16 rows x 192 keys
    f16x8 pf[6];
#pragma unroll
    for (int kc = 0; kc < 6; ++kc)
        pf[kc] = *(const f16x8*)((const char*)Pl + (w * 16 + f) * 400 + kc * 64 + g * 16);

    int tkey = kbase + tid;
    tkey = min(max(tkey, 0), SEQ - 1);
    const _Float16* vrow = Vb + ((long)(b * SEQ + tkey)) * EMB;
    _Float16* obase = Ob + ((long)(b * SEQ + q0 + w * 16 + g * 4)) * EMB;

    for (int ec = 0; ec < 8; ++ec) {
        __syncthreads(); // previous e-chunk's VT reads complete
        if (tid < 192) { // transpose-stage V chunk: VT[e][key]
#pragma unroll
            for (int p = 0; p < 8; ++p) {
                f16x8 vv = *(const f16x8*)(vrow + ec * 64 + p * 8);
#pragma unroll
                for (int i = 0; i < 8; ++i) VT[(p * 8 + i) * 200 + tid] = vv[i];
            }
        }
        __syncthreads();

        f32x4 pacc[4] = {};
#pragma unroll
        for (int kc = 0; kc < 6; ++kc) {
#pragma unroll
            for (int ni = 0; ni < 4; ++ni) {
                f16x8 vf = *(const f16x8*)((const char*)VT + (ni * 16 + f) * 400 + kc * 64 + g * 16);
                pacc[ni] = MFMA(pf[kc], vf, pacc[ni]);
            }
        }
#pragma unroll
        for (int ni = 0; ni < 4; ++ni)
#pragma unroll
            for (int j = 0; j < 4; ++j)
                obase[(long)j * EMB + ec * 64 + ni * 16 + f] = (_Float16)(pacc[ni][j] * rl[j]);
    }
}

extern "C" void kernel_launch(void* const* d_in, const int* in_sizes, int n_in,
                              void* d_out, int out_size, void* d_ws, size_t ws_size,
                              hipStream_t stream) {
    const float* x     = (const float*)d_in[0];
    const float* W_qkv = (const float*)d_in[1];
    const float* b_qkv = (const float*)d_in[2];
    const float* W_out = (const float*)d_in[3];
    const float* b_out = (const float*)d_in[4];

    char* ws = (char*)d_ws;
    _Float16* xb    = (_Float16*)(ws);                         // 16 MiB
    _Float16* WqkvT = (_Float16*)(ws + 16777216);              // 1.5 MiB
    _Float16* WoutT = (_Float16*)(ws + 16777216 + 1572864);    // 0.5 MiB
    _Float16* Qb    = (_Float16*)(ws + 18874368);              // 16 MiB
    _Float16* Kb    = (_Float16*)(ws + 18874368 + 16777216);   // 16 MiB
    _Float16* Vb    = (_Float16*)(ws + 18874368 + 33554432);   // 16 MiB
    _Float16* Ob    = xb; // reuse xb (dead after QKV GEMM)
    float* out = (float*)d_out;

    k_cast_x<<<4096, 256, 0, stream>>>(x, xb);
    k_transpose_cast<<<3072, 256, 0, stream>>>(W_qkv, WqkvT, 1536);
    k_transpose_cast<<<1024, 256, 0, stream>>>(W_out, WoutT, 512);

    dim3 g1(128, 12);
    k_gemm<0><<<g1, 256, 0, stream>>>(xb, WqkvT, b_qkv, Qb, Kb, Vb);

    k_attn<<<256, 256, 0, stream>>>(Qb, Kb, Vb, Ob);

    dim3 g2(128, 4);
    k_gemm<1><<<g2, 256, 0, stream>>>(Ob, WoutT, b_out, out, nullptr, nullptr);
}